// Round 1
// baseline (162.362 us; speedup 1.0000x reference)
//
#include <hip/hip_runtime.h>
#include <hip/hip_fp16.h>

typedef _Float16 f16;
typedef _Float16 f16x8 __attribute__((ext_vector_type(8)));
typedef _Float16 f16x4v __attribute__((ext_vector_type(4)));
typedef float f32x4 __attribute__((ext_vector_type(4)));
typedef unsigned int u32;
typedef u32 u32x4 __attribute__((ext_vector_type(4)));

constexpr int DM = 1024;
constexpr int HS = 64;
constexpr int NBATCH = 4;
constexpr int T = 4096;
// softmax uses exp2; fold the 1/sqrt(64)=0.125 score scale into the exponent constant
constexpr float CEXP = 0.18033688011112042f; // 0.125 * log2(e)

static __device__ __forceinline__ u32 pack2_f16(float a, float b) {
  union { f16 h[2]; u32 u; } cv;
  cv.h[0] = (f16)a; cv.h[1] = (f16)b;
  return cv.u;
}

// ---------------------------------------------------------------------------
// Prepass: W [1024][64] fp32  ->  WT [64][1024] fp16 (x3), so projection
// B-fragments are contiguous 16B loads.
// ---------------------------------------------------------------------------
__global__ void wtrans_kernel(const float* __restrict__ Wq, const float* __restrict__ Wk,
                              const float* __restrict__ Wv, f16* __restrict__ WT) {
  const int which = blockIdx.y;
  const float* __restrict__ W = (which == 0) ? Wq : ((which == 1) ? Wk : Wv);
  const int idx = blockIdx.x * 256 + threadIdx.x;   // 0 .. 65535
  const int k = idx >> 6, c = idx & 63;
  WT[which * (HS * DM) + c * DM + k] = (f16)W[idx];
}

// ---------------------------------------------------------------------------
// Projections: qh = q@Wq, kh = k@Wk (row-major [B*T][64] fp16),
// vhT = (v@Wv)^T ([B][64][T] fp16) so the PV MFMA A-operand is row-contiguous.
// MFMA 16x16x32 f16; each wave does 16 rows x 64 cols, K=1024.
// ---------------------------------------------------------------------------
__global__ __launch_bounds__(256) void proj_kernel(
    const float* __restrict__ xq, const float* __restrict__ xk, const float* __restrict__ xv,
    const f16* __restrict__ WT, f16* __restrict__ qh, f16* __restrict__ kh,
    f16* __restrict__ vhT) {
  const int which = blockIdx.y;
  const float* __restrict__ x = (which == 0) ? xq : ((which == 1) ? xk : xv);
  const f16* __restrict__ wt = WT + which * (HS * DM);
  const int lane = threadIdx.x & 63;
  const int w = threadIdx.x >> 6;
  const int q15 = lane & 15, g = lane >> 4;
  const int row0 = blockIdx.x * 64 + w * 16;
  const float* __restrict__ xrow = x + (size_t)(row0 + q15) * DM + 8 * g;

  f32x4 acc[4];
#pragma unroll
  for (int cb = 0; cb < 4; ++cb) acc[cb] = (f32x4){0.f, 0.f, 0.f, 0.f};

  for (int k0 = 0; k0 < DM; k0 += 32) {
    // A fragment: X[row = lane&15][k = k0 + 8g .. +7], fp32 -> fp16
    float4 a0 = *(const float4*)(xrow + k0);
    float4 a1 = *(const float4*)(xrow + k0 + 4);
    f16x8 af;
    af[0] = (f16)a0.x; af[1] = (f16)a0.y; af[2] = (f16)a0.z; af[3] = (f16)a0.w;
    af[4] = (f16)a1.x; af[5] = (f16)a1.y; af[6] = (f16)a1.z; af[7] = (f16)a1.w;
#pragma unroll
    for (int cb = 0; cb < 4; ++cb) {
      // B fragment: W[k][col] = WT[col][k], contiguous 16B per lane
      f16x8 bf = *(const f16x8*)(wt + (size_t)(cb * 16 + q15) * DM + k0 + 8 * g);
      acc[cb] = __builtin_amdgcn_mfma_f32_16x16x32_f16(af, bf, acc[cb], 0, 0, 0);
    }
  }

  if (which < 2) {
    f16* __restrict__ outp = (which == 0) ? qh : kh;
#pragma unroll
    for (int cb = 0; cb < 4; ++cb)
#pragma unroll
      for (int j = 0; j < 4; ++j)
        outp[(size_t)(row0 + 4 * g + j) * HS + cb * 16 + q15] = (f16)acc[cb][j];
  } else {
    // transposed store: vhT[b][d][t]; rows (t) are consecutive in j -> 8B packs
    const int b = row0 >> 12;            // /4096
    const int t0 = (row0 & (T - 1)) + 4 * g;
#pragma unroll
    for (int cb = 0; cb < 4; ++cb) {
      f16x4v pv;
#pragma unroll
      for (int j = 0; j < 4; ++j) pv[j] = (f16)acc[cb][j];
      *(f16x4v*)(vhT + (size_t)b * HS * T + (size_t)(cb * 16 + q15) * T + t0) = pv;
    }
  }
}

// ---------------------------------------------------------------------------
// Causal flash attention, swapped-operand form (S^T = K·Q^T, O^T = V^T·P^T).
// Block = 512 threads = 8 waves, all on ONE 16-row Q tile; waves split the
// KV blocks (64 rows each) round-robin and partials merge through LDS.
// No LDS staging of K/V: they are L2-resident (512KB/batch fp16).
// ---------------------------------------------------------------------------
__global__ __launch_bounds__(512) void attn_kernel(
    const f16* __restrict__ qh, const f16* __restrict__ kh,
    const f16* __restrict__ vhT, float* __restrict__ out) {
  __shared__ float sO[8][1088];   // [wave][d*17 + q], pad 17 -> conflict-free combine
  __shared__ float sM[8][16];
  __shared__ float sL[8][16];
  __shared__ float sS[8][16];

  const int tid = threadIdx.x;
  const int lane = tid & 63, w = tid >> 6;
  const int q15 = lane & 15, g = lane >> 4;
  const int q0 = blockIdx.x * 16;
  const int b = blockIdx.y;

  // Q as B-operand: lane holds Q[q=lane&15][d=8g+e]
  const f16* __restrict__ qrow = qh + (size_t)(b * T + q0 + q15) * HS + 8 * g;
  const f16x8 qb0 = *(const f16x8*)(qrow);
  const f16x8 qb1 = *(const f16x8*)(qrow + 32);
  const f16* __restrict__ kbase = kh + (size_t)b * T * HS;
  const f16* __restrict__ vbase = vhT + (size_t)b * HS * T;

  f32x4 o[4];
#pragma unroll
  for (int dt = 0; dt < 4; ++dt) o[dt] = (f32x4){0.f, 0.f, 0.f, 0.f};
  float m = -1e30f, lsum = 0.f;

  const int nblk = (q0 >> 6) + 1;   // causal: kv blocks 0 .. q0/64
  for (int blk = w; blk < nblk; blk += 8) {
    const int kv0 = blk << 6;
    // --- S^T = K·Q^T : lane holds S^T[k = kv0+kt*16+4g+j][q = lane&15]
    f32x4 s[4];
#pragma unroll
    for (int kt = 0; kt < 4; ++kt) {
      const f16* krow = kbase + (size_t)(kv0 + kt * 16 + q15) * HS + 8 * g;
      f16x8 ka0 = *(const f16x8*)(krow);
      f16x8 ka1 = *(const f16x8*)(krow + 32);
      f32x4 z = (f32x4){0.f, 0.f, 0.f, 0.f};
      z = __builtin_amdgcn_mfma_f32_16x16x32_f16(ka0, qb0, z, 0, 0, 0);
      z = __builtin_amdgcn_mfma_f32_16x16x32_f16(ka1, qb1, z, 0, 0, 0);
      s[kt] = z;
    }
    // --- causal mask (only the diagonal-crossing blocks)
    if (kv0 + 63 > q0) {
      const int qg = q0 + q15;
#pragma unroll
      for (int kt = 0; kt < 4; ++kt)
#pragma unroll
        for (int j = 0; j < 4; ++j)
          if (kv0 + kt * 16 + 4 * g + j > qg) s[kt][j] = -1e30f;
    }
    // --- online softmax for this 64-k block (per q column)
    float pmax = -1e30f;
#pragma unroll
    for (int kt = 0; kt < 4; ++kt)
#pragma unroll
      for (int j = 0; j < 4; ++j) pmax = fmaxf(pmax, s[kt][j]);
    pmax = fmaxf(pmax, __shfl_xor(pmax, 16));
    pmax = fmaxf(pmax, __shfl_xor(pmax, 32));
    const float mnew = fmaxf(m, pmax);
    const float r = exp2f((m - mnew) * CEXP);
    lsum *= r;
#pragma unroll
    for (int dt = 0; dt < 4; ++dt) o[dt] *= r;
    m = mnew;

    u32 pkv[8];                    // pkv[2*kt+jj] = fp16 pair (j=2jj, 2jj+1)
    float psum = 0.f;
#pragma unroll
    for (int kt = 0; kt < 4; ++kt) {
      float p0 = exp2f((s[kt][0] - mnew) * CEXP);
      float p1 = exp2f((s[kt][1] - mnew) * CEXP);
      float p2 = exp2f((s[kt][2] - mnew) * CEXP);
      float p3 = exp2f((s[kt][3] - mnew) * CEXP);
      psum += (p0 + p1) + (p2 + p3);
      pkv[2 * kt]     = pack2_f16(p0, p1);
      pkv[2 * kt + 1] = pack2_f16(p2, p3);
    }
    psum += __shfl_xor(psum, 16);
    psum += __shfl_xor(psum, 32);
    lsum += psum;

    // --- O^T += V^T · P^T
#pragma unroll
    for (int kc = 0; kc < 2; ++kc) {
      // build B-operand P^T[k = kc*32+8g+2r+{0,1}][q] via 2 bpermutes + select
      u32x4 bv;
#pragma unroll
      for (int r2 = 0; r2 < 4; ++r2) {
        const int sl = q15 + ((lane & 16) << 1) + 16 * (r2 >> 1);
        const u32 va = pkv[4 * kc + (r2 & 1)];        // source kt = 2kc   (pullers g<2)
        const u32 vb2 = pkv[4 * kc + 2 + (r2 & 1)];   // source kt = 2kc+1 (pullers g>=2)
        const u32 ra = (u32)__shfl((int)va, sl);
        const u32 rb = (u32)__shfl((int)vb2, sl);
        bv[r2] = (lane & 32) ? rb : ra;
      }
      union { u32x4 u; f16x8 f; } cv;
      cv.u = bv;
      const f16x8 pfrag = cv.f;
#pragma unroll
      for (int dt = 0; dt < 4; ++dt) {
        const f16* vrow = vbase + (size_t)(dt * 16 + q15) * T + kv0 + kc * 32 + 8 * g;
        f16x8 vf = *(const f16x8*)vrow;
        o[dt] = __builtin_amdgcn_mfma_f32_16x16x32_f16(vf, pfrag, o[dt], 0, 0, 0);
      }
    }
  }

  // --- merge the 8 waves' partials through LDS
#pragma unroll
  for (int dt = 0; dt < 4; ++dt)
#pragma unroll
    for (int j = 0; j < 4; ++j)
      sO[w][(dt * 16 + 4 * g + j) * 17 + q15] = o[dt][j];
  if (lane < 16) { sM[w][lane] = m; sL[w][lane] = lsum; }
  __syncthreads();

  if (tid < 16) {
    float M = -1e30f;
#pragma unroll
    for (int w2 = 0; w2 < 8; ++w2) M = fmaxf(M, sM[w2][tid]);
    float L = 0.f;
    float sc[8];
#pragma unroll
    for (int w2 = 0; w2 < 8; ++w2) {
      sc[w2] = exp2f((sM[w2][tid] - M) * CEXP);
      L += sL[w2][tid] * sc[w2];
    }
    const float invL = 1.f / L;
#pragma unroll
    for (int w2 = 0; w2 < 8; ++w2) sS[w2][tid] = sc[w2] * invL;
  }
  __syncthreads();

  const int d = tid & 63;
  const int qb2 = tid >> 6;
#pragma unroll
  for (int rep = 0; rep < 2; ++rep) {
    const int qi = qb2 + rep * 8;
    float acc2 = 0.f;
#pragma unroll
    for (int w2 = 0; w2 < 8; ++w2) acc2 += sO[w2][d * 17 + qi] * sS[w2][qi];
    out[(size_t)(b * T + q0 + qi) * HS + d] = acc2;
  }
}

// ---------------------------------------------------------------------------
extern "C" void kernel_launch(void* const* d_in, const int* in_sizes, int n_in,
                              void* d_out, int out_size, void* d_ws, size_t ws_size,
                              hipStream_t stream) {
  const float* q  = (const float*)d_in[0];
  const float* k  = (const float*)d_in[1];
  const float* v  = (const float*)d_in[2];
  const float* Wq = (const float*)d_in[3];
  const float* Wk = (const float*)d_in[4];
  const float* Wv = (const float*)d_in[5];
  // d_in[6] is the attn_mask: known lower-triangular causal; handled analytically.
  float* out = (float*)d_out;

  f16* qh  = (f16*)d_ws;                       // [B*T][64]
  f16* kh  = qh  + (size_t)NBATCH * T * HS;    // [B*T][64]
  f16* vhT = kh  + (size_t)NBATCH * T * HS;    // [B][64][T]
  f16* WT  = vhT + (size_t)NBATCH * T * HS;    // [3][64][1024]

  wtrans_kernel<<<dim3(256, 3), 256, 0, stream>>>(Wq, Wk, Wv, WT);
  proj_kernel<<<dim3(256, 3), 256, 0, stream>>>(q, k, v, WT, qh, kh, vhT);
  attn_kernel<<<dim3(T / 16, NBATCH), 512, 0, stream>>>(qh, kh, vhT, out);
}

// Round 2
// 121.977 us; speedup vs baseline: 1.3311x; 1.3311x over previous
//
#include <hip/hip_runtime.h>
#include <hip/hip_fp16.h>

typedef _Float16 f16;
typedef _Float16 f16x8 __attribute__((ext_vector_type(8)));
typedef _Float16 f16x4v __attribute__((ext_vector_type(4)));
typedef float f32x4 __attribute__((ext_vector_type(4)));
typedef float f32x16 __attribute__((ext_vector_type(16)));
typedef unsigned int u32;
typedef u32 u32x4 __attribute__((ext_vector_type(4)));

constexpr int DM = 1024;
constexpr int HS = 64;
constexpr int NBATCH = 4;
constexpr int T = 4096;
// softmax uses exp2; fold the 1/sqrt(64)=0.125 score scale into the exponent constant
constexpr float CEXP = 0.18033688011112042f; // 0.125 * log2(e)

#if __has_builtin(__builtin_amdgcn_exp2f)
#define EXP2(x) __builtin_amdgcn_exp2f(x)
#else
#define EXP2(x) exp2f(x)
#endif

static __device__ __forceinline__ u32 pack2_f16(float a, float b) {
  union { f16 h[2]; u32 u; } cv;
  cv.h[0] = (f16)a; cv.h[1] = (f16)b;
  return cv.u;
}

// ---------------------------------------------------------------------------
// Prepass: W [1024][64] fp32  ->  WT [64][1024] fp16 (x3)
// ---------------------------------------------------------------------------
__global__ void wtrans_kernel(const float* __restrict__ Wq, const float* __restrict__ Wk,
                              const float* __restrict__ Wv, f16* __restrict__ WT) {
  const int which = blockIdx.y;
  const float* __restrict__ W = (which == 0) ? Wq : ((which == 1) ? Wk : Wv);
  const int idx = blockIdx.x * 256 + threadIdx.x;   // 0 .. 65535
  const int k = idx >> 6, c = idx & 63;
  WT[which * (HS * DM) + c * DM + k] = (f16)W[idx];
}

// ---------------------------------------------------------------------------
// Projections with software-pipelined A loads (prefetch next 32-k chunk).
// qh/kh row-major [B*T][64] fp16; vhT transposed [B][64][T] fp16.
// ---------------------------------------------------------------------------
__global__ __launch_bounds__(256) void proj_kernel(
    const float* __restrict__ xq, const float* __restrict__ xk, const float* __restrict__ xv,
    const f16* __restrict__ WT, f16* __restrict__ qh, f16* __restrict__ kh,
    f16* __restrict__ vhT) {
  const int which = blockIdx.y;
  const float* __restrict__ x = (which == 0) ? xq : ((which == 1) ? xk : xv);
  const f16* __restrict__ wt = WT + which * (HS * DM);
  const int lane = threadIdx.x & 63;
  const int w = threadIdx.x >> 6;
  const int q15 = lane & 15, g = lane >> 4;
  const int row0 = blockIdx.x * 64 + w * 16;
  const float* __restrict__ xrow = x + (size_t)(row0 + q15) * DM + 8 * g;

  f32x4 acc[4];
#pragma unroll
  for (int cb = 0; cb < 4; ++cb) acc[cb] = (f32x4){0.f, 0.f, 0.f, 0.f};

  float4 a0 = *(const float4*)(xrow);
  float4 a1 = *(const float4*)(xrow + 4);

  for (int k0 = 0; k0 < DM - 32; k0 += 32) {
    float4 n0 = *(const float4*)(xrow + k0 + 32);
    float4 n1 = *(const float4*)(xrow + k0 + 36);
    f16x8 af;
    af[0] = (f16)a0.x; af[1] = (f16)a0.y; af[2] = (f16)a0.z; af[3] = (f16)a0.w;
    af[4] = (f16)a1.x; af[5] = (f16)a1.y; af[6] = (f16)a1.z; af[7] = (f16)a1.w;
#pragma unroll
    for (int cb = 0; cb < 4; ++cb) {
      f16x8 bf = *(const f16x8*)(wt + (size_t)(cb * 16 + q15) * DM + k0 + 8 * g);
      acc[cb] = __builtin_amdgcn_mfma_f32_16x16x32_f16(af, bf, acc[cb], 0, 0, 0);
    }
    a0 = n0; a1 = n1;
  }
  {
    const int k0 = DM - 32;
    f16x8 af;
    af[0] = (f16)a0.x; af[1] = (f16)a0.y; af[2] = (f16)a0.z; af[3] = (f16)a0.w;
    af[4] = (f16)a1.x; af[5] = (f16)a1.y; af[6] = (f16)a1.z; af[7] = (f16)a1.w;
#pragma unroll
    for (int cb = 0; cb < 4; ++cb) {
      f16x8 bf = *(const f16x8*)(wt + (size_t)(cb * 16 + q15) * DM + k0 + 8 * g);
      acc[cb] = __builtin_amdgcn_mfma_f32_16x16x32_f16(af, bf, acc[cb], 0, 0, 0);
    }
  }

  if (which < 2) {
    f16* __restrict__ outp = (which == 0) ? qh : kh;
#pragma unroll
    for (int cb = 0; cb < 4; ++cb)
#pragma unroll
      for (int j = 0; j < 4; ++j)
        outp[(size_t)(row0 + 4 * g + j) * HS + cb * 16 + q15] = (f16)acc[cb][j];
  } else {
    const int b = row0 >> 12;            // /4096
    const int t0 = (row0 & (T - 1)) + 4 * g;
#pragma unroll
    for (int cb = 0; cb < 4; ++cb) {
      f16x4v pv;
#pragma unroll
      for (int j = 0; j < 4; ++j) pv[j] = (f16)acc[cb][j];
      *(f16x4v*)(vhT + (size_t)b * HS * T + (size_t)(cb * 16 + q15) * T + t0) = pv;
    }
  }
}

// ---------------------------------------------------------------------------
// Causal flash attention v2: 32x32x16 MFMA, swapped form.
// Block = 512 threads = 8 waves on ONE 32-query tile; waves split KV blocks
// (32 keys each) round-robin; partials tree-merged in LDS under a common max.
// Grid: 1D 512, XCD-pinned batches (id%8 -> XCD pair per batch), big-first.
// ---------------------------------------------------------------------------
__global__ __launch_bounds__(512, 4) void attn_kernel(
    const f16* __restrict__ qh, const f16* __restrict__ kh,
    const f16* __restrict__ vhT, float* __restrict__ out) {
  __shared__ float sO[4][64][33];   // merge slots, pad 33 (2-way max on access)
  __shared__ float sMm[8][32];
  __shared__ float sLs[8][32];

  const int tid = threadIdx.x;
  const int lane = tid & 63, w = tid >> 6;
  const int q31 = lane & 31, hi = lane >> 5;

  const int id = blockIdx.x;                 // 0..511
  const int b = (id & 7) >> 1;               // batch pinned to XCD pair
  const int qt = 127 - 2 * (id >> 3) - (id & 1);   // big tiles dispatched first
  const int q0 = qt * 32;

  const f16* __restrict__ kbase = kh + (size_t)b * T * HS;
  const f16* __restrict__ vbase = vhT + (size_t)b * HS * T;
  const f16* __restrict__ qp = qh + (size_t)(b * T + q0 + q31) * HS + 8 * hi;

  // Q^T as B-operand: lane holds Q[q=lane&31][d = kt*16 + 8*hi + e]
  f16x8 qb[4];
#pragma unroll
  for (int kt = 0; kt < 4; ++kt) qb[kt] = *(const f16x8*)(qp + 16 * kt);

  f32x16 o0, o1;   // O^T d-tiles [0..31], [32..63]
#pragma unroll
  for (int i = 0; i < 16; ++i) { o0[i] = 0.f; o1[i] = 0.f; }
  float m = -1e30f, lsum = 0.f;

  const int nblk = qt + 1;   // causal: KV blocks 0 .. qt
  for (int blk = w; blk < nblk; blk += 8) {
    const int kv0 = blk * 32;
    // K as A-operand: lane holds K[key=kv0+(lane&31)][d = kt*16+8*hi+e]
    const f16* kr = kbase + (size_t)(kv0 + q31) * HS + 8 * hi;
    f16x8 ka0 = *(const f16x8*)(kr);
    f16x8 ka1 = *(const f16x8*)(kr + 16);
    f16x8 ka2 = *(const f16x8*)(kr + 32);
    f16x8 ka3 = *(const f16x8*)(kr + 48);

    f32x16 s;
#pragma unroll
    for (int i = 0; i < 16; ++i) s[i] = 0.f;
    s = __builtin_amdgcn_mfma_f32_32x32x16_f16(ka0, qb[0], s, 0, 0, 0);
    s = __builtin_amdgcn_mfma_f32_32x32x16_f16(ka1, qb[1], s, 0, 0, 0);
    s = __builtin_amdgcn_mfma_f32_32x32x16_f16(ka2, qb[2], s, 0, 0, 0);
    s = __builtin_amdgcn_mfma_f32_32x32x16_f16(ka3, qb[3], s, 0, 0, 0);
    // s[reg] = S^T[k = kv0 + (reg&3)+8*(reg>>2)+4*hi][q = q0 + q31]

    // V^T loads issued now, consumed after softmax (hide L2 latency)
    const f16* vr = vbase + (size_t)q31 * T + kv0 + 8 * hi;
    f16x8 v00 = *(const f16x8*)(vr);
    f16x8 v01 = *(const f16x8*)(vr + 16);
    f16x8 v10 = *(const f16x8*)(vr + (size_t)32 * T);
    f16x8 v11 = *(const f16x8*)(vr + (size_t)32 * T + 16);

    if (blk == qt) {   // diagonal block: mask key > q
#pragma unroll
      for (int r = 0; r < 16; ++r) {
        const int kl = (r & 3) + 8 * (r >> 2) + 4 * hi;
        if (kl > q31) s[r] = -1e30f;
      }
    }

    float pm = s[0];
#pragma unroll
    for (int r = 1; r < 16; ++r) pm = fmaxf(pm, s[r]);
    pm = fmaxf(pm, __shfl_xor(pm, 32));
    // defer-max (T13): skip O-rescale while max growth <= 32 (p <= 2^5.8, f16-safe)
    if (!__all(pm <= m + 32.f)) {
      const float mn = fmaxf(m, pm);
      const float r = EXP2((m - mn) * CEXP);
      lsum *= r;
#pragma unroll
      for (int i = 0; i < 16; ++i) { o0[i] *= r; o1[i] *= r; }
      m = mn;
    }

    float p[16];
    float ps = 0.f;
#pragma unroll
    for (int r = 0; r < 16; ++r) { p[r] = EXP2((s[r] - m) * CEXP); ps += p[r]; }
    ps += __shfl_xor(ps, 32);
    lsum += ps;

    // P^T -> fp16 B-fragments for keys [kv0..kv0+15], [kv0+16..kv0+31].
    // c[i] = pack(p[2i],p[2i+1]): lo-lane k-pairs {0,1}{2,3}{8,9}{10,11}{16..}..,
    // hi-lane +4. Cross-half exchange + select rebuilds B layout k=8*hi+e.
    u32 c[8], x[8];
#pragma unroll
    for (int i = 0; i < 8; ++i) c[i] = pack2_f16(p[2 * i], p[2 * i + 1]);
#pragma unroll
    for (int i = 0; i < 8; ++i) x[i] = (u32)__shfl_xor((int)c[i], 32);
    union { u32x4 u; f16x8 f; } f1, f2;
    f1.u = (u32x4){ hi ? x[2] : c[0], hi ? x[3] : c[1], hi ? c[2] : x[0], hi ? c[3] : x[1] };
    f2.u = (u32x4){ hi ? x[6] : c[4], hi ? x[7] : c[5], hi ? c[6] : x[4], hi ? c[7] : x[5] };

    o0 = __builtin_amdgcn_mfma_f32_32x32x16_f16(v00, f1.f, o0, 0, 0, 0);
    o0 = __builtin_amdgcn_mfma_f32_32x32x16_f16(v01, f2.f, o0, 0, 0, 0);
    o1 = __builtin_amdgcn_mfma_f32_32x32x16_f16(v10, f1.f, o1, 0, 0, 0);
    o1 = __builtin_amdgcn_mfma_f32_32x32x16_f16(v11, f2.f, o1, 0, 0, 0);
  }

  // ---- cross-wave merge under common max M ----
  if (lane < 32) sMm[w][q31] = m;
  __syncthreads();
  float M = sMm[0][q31];
#pragma unroll
  for (int w2 = 1; w2 < 8; ++w2) M = fmaxf(M, sMm[w2][q31]);
  const float sc = EXP2((m - M) * CEXP);   // idle waves: exp2(-huge)=0
  if (lane < 32) sLs[w][q31] = lsum * sc;
#pragma unroll
  for (int i = 0; i < 16; ++i) { o0[i] *= sc; o1[i] *= sc; }

  if (w >= 4) {
#pragma unroll
    for (int r = 0; r < 16; ++r) {
      const int d = (r & 3) + 8 * (r >> 2) + 4 * hi;
      sO[w - 4][d][q31] = o0[r];
      sO[w - 4][d + 32][q31] = o1[r];
    }
  }
  __syncthreads();
  if (w < 4) {
#pragma unroll
    for (int r = 0; r < 16; ++r) {
      const int d = (r & 3) + 8 * (r >> 2) + 4 * hi;
      sO[w][d][q31] += o0[r];
      sO[w][d + 32][q31] += o1[r];
    }
  }
  __syncthreads();

  // ---- normalize + coalesced float4 store: thread -> (q = tid>>4, d0 = (tid&15)*4)
  const int q = tid >> 4;
  const int d0 = (tid & 15) * 4;
  float L = 0.f;
#pragma unroll
  for (int w2 = 0; w2 < 8; ++w2) L += sLs[w2][q];
  const float invL = 1.f / L;
  float4 rv;
  rv.x = (sO[0][d0 + 0][q] + sO[1][d0 + 0][q] + sO[2][d0 + 0][q] + sO[3][d0 + 0][q]) * invL;
  rv.y = (sO[0][d0 + 1][q] + sO[1][d0 + 1][q] + sO[2][d0 + 1][q] + sO[3][d0 + 1][q]) * invL;
  rv.z = (sO[0][d0 + 2][q] + sO[1][d0 + 2][q] + sO[2][d0 + 2][q] + sO[3][d0 + 2][q]) * invL;
  rv.w = (sO[0][d0 + 3][q] + sO[1][d0 + 3][q] + sO[2][d0 + 3][q] + sO[3][d0 + 3][q]) * invL;
  *(float4*)(out + (size_t)(b * T + q0 + q) * HS + d0) = rv;
}

// ---------------------------------------------------------------------------
extern "C" void kernel_launch(void* const* d_in, const int* in_sizes, int n_in,
                              void* d_out, int out_size, void* d_ws, size_t ws_size,
                              hipStream_t stream) {
  const float* q  = (const float*)d_in[0];
  const float* k  = (const float*)d_in[1];
  const float* v  = (const float*)d_in[2];
  const float* Wq = (const float*)d_in[3];
  const float* Wk = (const float*)d_in[4];
  const float* Wv = (const float*)d_in[5];
  // d_in[6] attn_mask: known lower-triangular causal; handled analytically.
  float* out = (float*)d_out;

  f16* qh  = (f16*)d_ws;                       // [B*T][64]
  f16* kh  = qh  + (size_t)NBATCH * T * HS;    // [B*T][64]
  f16* vhT = kh  + (size_t)NBATCH * T * HS;    // [B][64][T]
  f16* WT  = vhT + (size_t)NBATCH * T * HS;    // [3][64][1024]

  wtrans_kernel<<<dim3(256, 3), 256, 0, stream>>>(Wq, Wk, Wv, WT);
  proj_kernel<<<dim3(256, 3), 256, 0, stream>>>(q, k, v, WT, qh, kh, vhT);
  attn_kernel<<<dim3(T / 32 * NBATCH), 512, 0, stream>>>(qh, kh, vhT, out);
}

// Round 4
// 121.739 us; speedup vs baseline: 1.3337x; 1.0020x over previous
//
#include <hip/hip_runtime.h>
#include <hip/hip_fp16.h>

typedef _Float16 f16;
typedef __fp16 h16x2 __attribute__((ext_vector_type(2)));
typedef _Float16 f16x8 __attribute__((ext_vector_type(8)));
typedef _Float16 f16x4v __attribute__((ext_vector_type(4)));
typedef float f32x4 __attribute__((ext_vector_type(4)));
typedef float f32x16 __attribute__((ext_vector_type(16)));
typedef unsigned int u32;
typedef u32 u32x4 __attribute__((ext_vector_type(4)));

constexpr int DM = 1024;
constexpr int HS = 64;
constexpr int NBATCH = 4;
constexpr int T = 4096;
// softmax uses exp2; fold the 1/sqrt(64)=0.125 score scale into the exponent constant
constexpr float CEXP = 0.18033688011112042f; // 0.125 * log2(e)

#if __has_builtin(__builtin_amdgcn_exp2f)
#define EXP2(x) __builtin_amdgcn_exp2f(x)
#else
#define EXP2(x) exp2f(x)
#endif

static __device__ __forceinline__ u32 pack2_f16(float a, float b) {
  union { f16 h[2]; u32 u; } cv;
  cv.h[0] = (f16)a; cv.h[1] = (f16)b;
  return cv.u;
}

// pack 8 floats -> f16x8 via 4x v_cvt_pkrtz (half the VALU of 16 scalar cvts)
static __device__ __forceinline__ f16x8 cvt8(const float4& a0, const float4& a1) {
  union { h16x2 p[4]; f16x8 v; } cv;
  cv.p[0] = __builtin_amdgcn_cvt_pkrtz(a0.x, a0.y);
  cv.p[1] = __builtin_amdgcn_cvt_pkrtz(a0.z, a0.w);
  cv.p[2] = __builtin_amdgcn_cvt_pkrtz(a1.x, a1.y);
  cv.p[3] = __builtin_amdgcn_cvt_pkrtz(a1.z, a1.w);
  return cv.v;
}

// ---------------------------------------------------------------------------
// Prepass: W [1024][64] fp32  ->  WT [64][1024] fp16 (x3)
// ---------------------------------------------------------------------------
__global__ void wtrans_kernel(const float* __restrict__ Wq, const float* __restrict__ Wk,
                              const float* __restrict__ Wv, f16* __restrict__ WT) {
  const int which = blockIdx.y;
  const float* __restrict__ W = (which == 0) ? Wq : ((which == 1) ? Wk : Wv);
  const int idx = blockIdx.x * 256 + threadIdx.x;   // 0 .. 65535
  const int k = idx >> 6, c = idx & 63;
  WT[which * (HS * DM) + c * DM + k] = (f16)W[idx];
}

// ---------------------------------------------------------------------------
// Projections, fully software-pipelined: BOTH A (x, fp32 HBM stream) and B
// (WT fragments, L2) are prefetched one K-step ahead with two named buffer
// sets (manual unroll x2 -> no register moves, all indices static).
// Per-iteration wait is then vmcnt(6): next-iter loads stay in flight across
// the MFMA cluster instead of draining every step (the round-2 101us bug).
// ---------------------------------------------------------------------------
__global__ __launch_bounds__(256) void proj_kernel(
    const float* __restrict__ xq, const float* __restrict__ xk, const float* __restrict__ xv,
    const f16* __restrict__ WT, f16* __restrict__ qh, f16* __restrict__ kh,
    f16* __restrict__ vhT) {
  const int which = blockIdx.y;
  const float* __restrict__ x = (which == 0) ? xq : ((which == 1) ? xk : xv);
  const f16* __restrict__ wt = WT + which * (HS * DM);
  const int lane = threadIdx.x & 63;
  const int w = threadIdx.x >> 6;
  const int q15 = lane & 15, g = lane >> 4;
  const int row0 = blockIdx.x * 64 + w * 16;
  const float* __restrict__ xrow = x + (size_t)(row0 + q15) * DM + 8 * g;
  const f16* __restrict__ wtb0 = wt + (size_t)(0 * 16 + q15) * DM + 8 * g;
  const f16* __restrict__ wtb1 = wt + (size_t)(1 * 16 + q15) * DM + 8 * g;
  const f16* __restrict__ wtb2 = wt + (size_t)(2 * 16 + q15) * DM + 8 * g;
  const f16* __restrict__ wtb3 = wt + (size_t)(3 * 16 + q15) * DM + 8 * g;

  f32x4 acc[4];
#pragma unroll
  for (int cb = 0; cb < 4; ++cb) acc[cb] = (f32x4){0.f, 0.f, 0.f, 0.f};

  // stage A buffers (k-step 0)
  float4 aA0 = *(const float4*)(xrow);
  float4 aA1 = *(const float4*)(xrow + 4);
  f16x8 bA0 = *(const f16x8*)(wtb0);
  f16x8 bA1 = *(const f16x8*)(wtb1);
  f16x8 bA2 = *(const f16x8*)(wtb2);
  f16x8 bA3 = *(const f16x8*)(wtb3);
  float4 aB0, aB1;
  f16x8 bB0, bB1, bB2, bB3;

  for (int k0 = 0; k0 < DM; k0 += 64) {
    // ---- half 1: prefetch k0+32 into B-set, compute A-set
    {
      aB0 = *(const float4*)(xrow + k0 + 32);
      aB1 = *(const float4*)(xrow + k0 + 36);
      bB0 = *(const f16x8*)(wtb0 + k0 + 32);
      bB1 = *(const f16x8*)(wtb1 + k0 + 32);
      bB2 = *(const f16x8*)(wtb2 + k0 + 32);
      bB3 = *(const f16x8*)(wtb3 + k0 + 32);
      const f16x8 af = cvt8(aA0, aA1);
      acc[0] = __builtin_amdgcn_mfma_f32_16x16x32_f16(af, bA0, acc[0], 0, 0, 0);
      acc[1] = __builtin_amdgcn_mfma_f32_16x16x32_f16(af, bA1, acc[1], 0, 0, 0);
      acc[2] = __builtin_amdgcn_mfma_f32_16x16x32_f16(af, bA2, acc[2], 0, 0, 0);
      acc[3] = __builtin_amdgcn_mfma_f32_16x16x32_f16(af, bA3, acc[3], 0, 0, 0);
    }
    // ---- half 2: prefetch k0+64 into A-set (guarded), compute B-set
    {
      if (k0 < DM - 64) {
        aA0 = *(const float4*)(xrow + k0 + 64);
        aA1 = *(const float4*)(xrow + k0 + 68);
        bA0 = *(const f16x8*)(wtb0 + k0 + 64);
        bA1 = *(const f16x8*)(wtb1 + k0 + 64);
        bA2 = *(const f16x8*)(wtb2 + k0 + 64);
        bA3 = *(const f16x8*)(wtb3 + k0 + 64);
      }
      const f16x8 af = cvt8(aB0, aB1);
      acc[0] = __builtin_amdgcn_mfma_f32_16x16x32_f16(af, bB0, acc[0], 0, 0, 0);
      acc[1] = __builtin_amdgcn_mfma_f32_16x16x32_f16(af, bB1, acc[1], 0, 0, 0);
      acc[2] = __builtin_amdgcn_mfma_f32_16x16x32_f16(af, bB2, acc[2], 0, 0, 0);
      acc[3] = __builtin_amdgcn_mfma_f32_16x16x32_f16(af, bB3, acc[3], 0, 0, 0);
    }
  }

  if (which < 2) {
    f16* __restrict__ outp = (which == 0) ? qh : kh;
#pragma unroll
    for (int cb = 0; cb < 4; ++cb)
#pragma unroll
      for (int j = 0; j < 4; ++j)
        outp[(size_t)(row0 + 4 * g + j) * HS + cb * 16 + q15] = (f16)acc[cb][j];
  } else {
    const int b = row0 >> 12;            // /4096
    const int t0 = (row0 & (T - 1)) + 4 * g;
#pragma unroll
    for (int cb = 0; cb < 4; ++cb) {
      f16x4v pv;
#pragma unroll
      for (int j = 0; j < 4; ++j) pv[j] = (f16)acc[cb][j];
      *(f16x4v*)(vhT + (size_t)b * HS * T + (size_t)(cb * 16 + q15) * T + t0) = pv;
    }
  }
}

// ---------------------------------------------------------------------------
// Causal flash attention v2: 32x32x16 MFMA, swapped form.
// Block = 512 threads = 8 waves on ONE 32-query tile; waves split KV blocks
// (32 keys each) round-robin; partials tree-merged in LDS under a common max.
// Grid: 1D 512, XCD-pinned batches (id%8 -> XCD pair per batch), big-first.
// ---------------------------------------------------------------------------
__global__ __launch_bounds__(512, 4) void attn_kernel(
    const f16* __restrict__ qh, const f16* __restrict__ kh,
    const f16* __restrict__ vhT, float* __restrict__ out) {
  __shared__ float sO[4][64][33];   // merge slots, pad 33 (2-way max on access)
  __shared__ float sMm[8][32];
  __shared__ float sLs[8][32];

  const int tid = threadIdx.x;
  const int lane = tid & 63, w = tid >> 6;
  const int q31 = lane & 31, hi = lane >> 5;

  const int id = blockIdx.x;                 // 0..511
  const int b = (id & 7) >> 1;               // batch pinned to XCD pair
  const int qt = 127 - 2 * (id >> 3) - (id & 1);   // big tiles dispatched first
  const int q0 = qt * 32;

  const f16* __restrict__ kbase = kh + (size_t)b * T * HS;
  const f16* __restrict__ vbase = vhT + (size_t)b * HS * T;
  const f16* __restrict__ qp = qh + (size_t)(b * T + q0 + q31) * HS + 8 * hi;

  // Q^T as B-operand: lane holds Q[q=lane&31][d = kt*16 + 8*hi + e]
  f16x8 qb[4];
#pragma unroll
  for (int kt = 0; kt < 4; ++kt) qb[kt] = *(const f16x8*)(qp + 16 * kt);

  f32x16 o0, o1;   // O^T d-tiles [0..31], [32..63]
#pragma unroll
  for (int i = 0; i < 16; ++i) { o0[i] = 0.f; o1[i] = 0.f; }
  float m = -1e30f, lsum = 0.f;

  const int nblk = qt + 1;   // causal: KV blocks 0 .. qt
  for (int blk = w; blk < nblk; blk += 8) {
    const int kv0 = blk * 32;
    // K as A-operand: lane holds K[key=kv0+(lane&31)][d = kt*16+8*hi+e]
    const f16* kr = kbase + (size_t)(kv0 + q31) * HS + 8 * hi;
    f16x8 ka0 = *(const f16x8*)(kr);
    f16x8 ka1 = *(const f16x8*)(kr + 16);
    f16x8 ka2 = *(const f16x8*)(kr + 32);
    f16x8 ka3 = *(const f16x8*)(kr + 48);

    f32x16 s;
#pragma unroll
    for (int i = 0; i < 16; ++i) s[i] = 0.f;
    s = __builtin_amdgcn_mfma_f32_32x32x16_f16(ka0, qb[0], s, 0, 0, 0);
    s = __builtin_amdgcn_mfma_f32_32x32x16_f16(ka1, qb[1], s, 0, 0, 0);
    s = __builtin_amdgcn_mfma_f32_32x32x16_f16(ka2, qb[2], s, 0, 0, 0);
    s = __builtin_amdgcn_mfma_f32_32x32x16_f16(ka3, qb[3], s, 0, 0, 0);
    // s[reg] = S^T[k = kv0 + (reg&3)+8*(reg>>2)+4*hi][q = q0 + q31]

    // V^T loads issued now, consumed after softmax (hide L2 latency)
    const f16* vr = vbase + (size_t)q31 * T + kv0 + 8 * hi;
    f16x8 v00 = *(const f16x8*)(vr);
    f16x8 v01 = *(const f16x8*)(vr + 16);
    f16x8 v10 = *(const f16x8*)(vr + (size_t)32 * T);
    f16x8 v11 = *(const f16x8*)(vr + (size_t)32 * T + 16);

    if (blk == qt) {   // diagonal block: mask key > q
#pragma unroll
      for (int r = 0; r < 16; ++r) {
        const int kl = (r & 3) + 8 * (r >> 2) + 4 * hi;
        if (kl > q31) s[r] = -1e30f;
      }
    }

    float pm = s[0];
#pragma unroll
    for (int r = 1; r < 16; ++r) pm = fmaxf(pm, s[r]);
    pm = fmaxf(pm, __shfl_xor(pm, 32));
    // defer-max (T13): skip O-rescale while max growth <= 32 (p <= 2^5.8, f16-safe)
    if (!__all(pm <= m + 32.f)) {
      const float mn = fmaxf(m, pm);
      const float r = EXP2((m - mn) * CEXP);
      lsum *= r;
#pragma unroll
      for (int i = 0; i < 16; ++i) { o0[i] *= r; o1[i] *= r; }
      m = mn;
    }

    float p[16];
    float ps = 0.f;
#pragma unroll
    for (int r = 0; r < 16; ++r) { p[r] = EXP2((s[r] - m) * CEXP); ps += p[r]; }
    ps += __shfl_xor(ps, 32);
    lsum += ps;

    // P^T -> fp16 B-fragments for keys [kv0..kv0+15], [kv0+16..kv0+31].
    // c[i] = pack(p[2i],p[2i+1]): lo-lane k-pairs {0,1}{2,3}{8,9}{10,11}{16..}..,
    // hi-lane +4. Cross-half exchange + select rebuilds B layout k=8*hi+e.
    u32 c[8], x[8];
#pragma unroll
    for (int i = 0; i < 8; ++i) c[i] = pack2_f16(p[2 * i], p[2 * i + 1]);
#pragma unroll
    for (int i = 0; i < 8; ++i) x[i] = (u32)__shfl_xor((int)c[i], 32);
    union { u32x4 u; f16x8 f; } f1, f2;
    f1.u = (u32x4){ hi ? x[2] : c[0], hi ? x[3] : c[1], hi ? c[2] : x[0], hi ? c[3] : x[1] };
    f2.u = (u32x4){ hi ? x[6] : c[4], hi ? x[7] : c[5], hi ? c[6] : x[4], hi ? c[7] : x[5] };

    o0 = __builtin_amdgcn_mfma_f32_32x32x16_f16(v00, f1.f, o0, 0, 0, 0);
    o0 = __builtin_amdgcn_mfma_f32_32x32x16_f16(v01, f2.f, o0, 0, 0, 0);
    o1 = __builtin_amdgcn_mfma_f32_32x32x16_f16(v10, f1.f, o1, 0, 0, 0);
    o1 = __builtin_amdgcn_mfma_f32_32x32x16_f16(v11, f2.f, o1, 0, 0, 0);
  }

  // ---- cross-wave merge under common max M ----
  if (lane < 32) sMm[w][q31] = m;
  __syncthreads();
  float M = sMm[0][q31];
#pragma unroll
  for (int w2 = 1; w2 < 8; ++w2) M = fmaxf(M, sMm[w2][q31]);
  const float sc = EXP2((m - M) * CEXP);   // idle waves: exp2(-huge)=0
  if (lane < 32) sLs[w][q31] = lsum * sc;
#pragma unroll
  for (int i = 0; i < 16; ++i) { o0[i] *= sc; o1[i] *= sc; }

  if (w >= 4) {
#pragma unroll
    for (int r = 0; r < 16; ++r) {
      const int d = (r & 3) + 8 * (r >> 2) + 4 * hi;
      sO[w - 4][d][q31] = o0[r];
      sO[w - 4][d + 32][q31] = o1[r];
    }
  }
  __syncthreads();
  if (w < 4) {
#pragma unroll
    for (int r = 0; r < 16; ++r) {
      const int d = (r & 3) + 8 * (r >> 2) + 4 * hi;
      sO[w][d][q31] += o0[r];
      sO[w][d + 32][q31] += o1[r];
    }
  }
  __syncthreads();

  // ---- normalize + coalesced float4 store: thread -> (q = tid>>4, d0 = (tid&15)*4)
  const int q = tid >> 4;
  const int d0 = (tid & 15) * 4;
  float L = 0.f;
#pragma unroll
  for (int w2 = 0; w2 < 8; ++w2) L += sLs[w2][q];
  const float invL = 1.f / L;
  float4 rv;
  rv.x = (sO[0][d0 + 0][q] + sO[1][d0 + 0][q] + sO[2][d0 + 0][q] + sO[3][d0 + 0][q]) * invL;
  rv.y = (sO[0][d0 + 1][q] + sO[1][d0 + 1][q] + sO[2][d0 + 1][q] + sO[3][d0 + 1][q]) * invL;
  rv.z = (sO[0][d0 + 2][q] + sO[1][d0 + 2][q] + sO[2][d0 + 2][q] + sO[3][d0 + 2][q]) * invL;
  rv.w = (sO[0][d0 + 3][q] + sO[1][d0 + 3][q] + sO[2][d0 + 3][q] + sO[3][d0 + 3][q]) * invL;
  *(float4*)(out + (size_t)(b * T + q0 + q) * HS + d0) = rv;
}

// ---------------------------------------------------------------------------
extern "C" void kernel_launch(void* const* d_in, const int* in_sizes, int n_in,
                              void* d_out, int out_size, void* d_ws, size_t ws_size,
                              hipStream_t stream) {
  const float* q  = (const float*)d_in[0];
  const float* k  = (const float*)d_in[1];
  const float* v  = (const float*)d_in[2];
  const float* Wq = (const float*)d_in[3];
  const float* Wk = (const float*)d_in[4];
  const float* Wv = (const float*)d_in[5];
  // d_in[6] attn_mask: known lower-triangular causal; handled analytically.
  float* out = (float*)d_out;

  f16* qh  = (f16*)d_ws;                       // [B*T][64]
  f16* kh  = qh  + (size_t)NBATCH * T * HS;    // [B*T][64]
  f16* vhT = kh  + (size_t)NBATCH * T * HS;    // [B][64][T]
  f16* WT  = vhT + (size_t)NBATCH * T * HS;    // [3][64][1024]

  wtrans_kernel<<<dim3(256, 3), 256, 0, stream>>>(Wq, Wk, Wv, WT);
  proj_kernel<<<dim3(256, 3), 256, 0, stream>>>(q, k, v, WT, qh, kh, vhT);
  attn_kernel<<<dim3(T / 32 * NBATCH), 512, 0, stream>>>(qh, kh, vhT, out);
}

// Round 5
// 87.038 us; speedup vs baseline: 1.8654x; 1.3987x over previous
//
#include <hip/hip_runtime.h>
#include <hip/hip_fp16.h>

typedef _Float16 f16;
typedef __fp16 h16x2 __attribute__((ext_vector_type(2)));
typedef _Float16 f16x8 __attribute__((ext_vector_type(8)));
typedef _Float16 f16x4v __attribute__((ext_vector_type(4)));
typedef float f32x4 __attribute__((ext_vector_type(4)));
typedef float f32x16 __attribute__((ext_vector_type(16)));
typedef unsigned int u32;
typedef u32 u32x4 __attribute__((ext_vector_type(4)));

constexpr int DM = 1024;
constexpr int HS = 64;
constexpr int NBATCH = 4;
constexpr int T = 4096;
// softmax uses exp2; fold the 1/sqrt(64)=0.125 score scale into the exponent constant
constexpr float CEXP = 0.18033688011112042f; // 0.125 * log2(e)

#if __has_builtin(__builtin_amdgcn_exp2f)
#define EXP2(x) __builtin_amdgcn_exp2f(x)
#else
#define EXP2(x) exp2f(x)
#endif

static __device__ __forceinline__ u32 pack2_f16(float a, float b) {
  union { f16 h[2]; u32 u; } cv;
  cv.h[0] = (f16)a; cv.h[1] = (f16)b;
  return cv.u;
}

// pack 8 floats -> f16x8 via 4x v_cvt_pkrtz
static __device__ __forceinline__ f16x8 cvt8(const f32x4& a0, const f32x4& a1) {
  union { h16x2 p[4]; f16x8 v; } cv;
  cv.p[0] = __builtin_amdgcn_cvt_pkrtz(a0[0], a0[1]);
  cv.p[1] = __builtin_amdgcn_cvt_pkrtz(a0[2], a0[3]);
  cv.p[2] = __builtin_amdgcn_cvt_pkrtz(a1[0], a1[1]);
  cv.p[3] = __builtin_amdgcn_cvt_pkrtz(a1[2], a1[3]);
  return cv.v;
}

// async global->LDS, 16B per lane: LDS dest = wave-uniform base + lane*16,
// global src is per-lane (pre-swizzled). Compiler cannot sink/serialize these.
static __device__ __forceinline__ void gload_lds16(const void* g, void* l) {
  __builtin_amdgcn_global_load_lds(
      (__attribute__((address_space(1))) void*)(g),
      (__attribute__((address_space(3))) void*)(l), 16, 0, 0);
}

// ---------------------------------------------------------------------------
// Prepass: W [1024][64] fp32  ->  WT [64][1024] fp16 (x3)
// ---------------------------------------------------------------------------
__global__ void wtrans_kernel(const float* __restrict__ Wq, const float* __restrict__ Wk,
                              const float* __restrict__ Wv, f16* __restrict__ WT) {
  const int which = blockIdx.y;
  const float* __restrict__ W = (which == 0) ? Wq : ((which == 1) ? Wk : Wv);
  const int idx = blockIdx.x * 256 + threadIdx.x;   // 0 .. 65535
  const int k = idx >> 6, c = idx & 63;
  WT[which * (HS * DM) + c * DM + k] = (f16)W[idx];
}

// ---------------------------------------------------------------------------
// Projections v3: LDS-staged via global_load_lds (async DMA), 2-phase double
// buffer. Block = 256 thr = 4 waves, tile = 64 rows x 64 k per chunk, 16
// chunks. A [64r][64k] f32 16KB, B [64c][64k] f16 8KB, both x2 = 48KB LDS
// -> 3 blocks/CU. ds_read conflicts fixed by XOR-swizzling the k-granule
// with (row&7) / (col&7), applied on the per-lane GLOBAL source address
// (LDS dest stays linear — rule both-sides-or-neither).
// ---------------------------------------------------------------------------
__global__ __launch_bounds__(256, 3) void proj_kernel(
    const float* __restrict__ xq, const float* __restrict__ xk, const float* __restrict__ xv,
    const f16* __restrict__ WT, f16* __restrict__ qh, f16* __restrict__ kh,
    f16* __restrict__ vhT) {
  __shared__ char As[2][16384];
  __shared__ char Bs[2][8192];

  const int which = blockIdx.y;
  const float* __restrict__ x = (which == 0) ? xq : ((which == 1) ? xk : xv);
  const f16* __restrict__ wt = WT + which * (HS * DM);
  const int tid = threadIdx.x;
  const int lane = tid & 63, w = tid >> 6;
  const int q15 = lane & 15, g = lane >> 4;
  const int rowblk = blockIdx.x * 64;
  const char* __restrict__ xb = (const char*)(x + (size_t)rowblk * DM);
  const char* __restrict__ wb = (const char*)wt;

  // per-lane staging source offsets (constant across t)
  // A: chunk c = w*4+i covers rows 4c..4c+3; lane -> row 4c+(l>>4), k-quad
  //    stored at granule (l&15), content quad (l&15)^(row&7).
  int aRow[4], aGa[4];
#pragma unroll
  for (int i = 0; i < 4; ++i) {
    const int c = w * 4 + i;
    aRow[i] = c * 4 + (lane >> 4);
    aGa[i] = (lane & 15) ^ (aRow[i] & 7);
  }
  // B: chunk c = w*2+i covers cols 8c..8c+7; lane -> col 8c+(l>>3), k-octet
  //    stored at granule (l&7), content octet (l&7)^((l>>3)&7).
  const int bo = (lane & 7) ^ ((lane >> 3) & 7);

  f32x4 acc[4];
#pragma unroll
  for (int cb = 0; cb < 4; ++cb) acc[cb] = (f32x4){0.f, 0.f, 0.f, 0.f};

#define STAGE(buf, t)                                                          \
  {                                                                            \
    _Pragma("unroll") for (int i = 0; i < 4; ++i) {                            \
      const int c = w * 4 + i;                                                 \
      gload_lds16(xb + (size_t)aRow[i] * 4096 + (t) * 256 + aGa[i] * 16,       \
                  &As[buf][c * 1024]);                                         \
    }                                                                          \
    _Pragma("unroll") for (int i = 0; i < 2; ++i) {                            \
      const int c = w * 2 + i;                                                 \
      const int col = c * 8 + (lane >> 3);                                     \
      gload_lds16(wb + (size_t)col * 2048 + (t) * 128 + bo * 16,               \
                  &Bs[buf][c * 1024]);                                         \
    }                                                                          \
  }

#define COMPUTE(buf)                                                           \
  {                                                                            \
    const int rw = w * 16 + q15;                                               \
    const char* pa = &As[buf][rw * 256];                                       \
    const int rx = q15 & 7;                                                    \
    _Pragma("unroll") for (int s = 0; s < 2; ++s) {                            \
      const int qa = 8 * s + 2 * g;                                            \
      f32x4 a0 = *(const f32x4*)(pa + ((qa ^ rx) * 16));                       \
      f32x4 a1 = *(const f32x4*)(pa + (((qa + 1) ^ rx) * 16));                 \
      const f16x8 af = cvt8(a0, a1);                                           \
      _Pragma("unroll") for (int cb = 0; cb < 4; ++cb) {                       \
        const int col = cb * 16 + q15;                                         \
        const int gi = (4 * s + g) ^ rx;                                       \
        const f16x8 bf = *(const f16x8*)(&Bs[buf][col * 128 + gi * 16]);       \
        acc[cb] = __builtin_amdgcn_mfma_f32_16x16x32_f16(af, bf, acc[cb], 0, 0, 0); \
      }                                                                        \
    }                                                                          \
  }

  STAGE(0, 0);
  __syncthreads();
  for (int t = 0; t < 16; ++t) {
    if (t < 15) STAGE((t + 1) & 1, t + 1);
    COMPUTE(t & 1);
    __syncthreads();
  }
#undef STAGE
#undef COMPUTE

  if (which < 2) {
    f16* __restrict__ outp = (which == 0) ? qh : kh;
    const int row0 = rowblk + w * 16;
#pragma unroll
    for (int cb = 0; cb < 4; ++cb)
#pragma unroll
      for (int j = 0; j < 4; ++j)
        outp[(size_t)(row0 + 4 * g + j) * HS + cb * 16 + q15] = (f16)acc[cb][j];
  } else {
    const int row0 = rowblk + w * 16;
    const int b = row0 >> 12;            // /4096
    const int t0 = (row0 & (T - 1)) + 4 * g;
#pragma unroll
    for (int cb = 0; cb < 4; ++cb) {
      f16x4v pv;
#pragma unroll
      for (int j = 0; j < 4; ++j) pv[j] = (f16)acc[cb][j];
      *(f16x4v*)(vhT + (size_t)b * HS * T + (size_t)(cb * 16 + q15) * T + t0) = pv;
    }
  }
}

// ---------------------------------------------------------------------------
// Causal flash attention v2: 32x32x16 MFMA, swapped form. (unchanged)
// ---------------------------------------------------------------------------
__global__ __launch_bounds__(512, 4) void attn_kernel(
    const f16* __restrict__ qh, const f16* __restrict__ kh,
    const f16* __restrict__ vhT, float* __restrict__ out) {
  __shared__ float sO[4][64][33];   // merge slots, pad 33
  __shared__ float sMm[8][32];
  __shared__ float sLs[8][32];

  const int tid = threadIdx.x;
  const int lane = tid & 63, w = tid >> 6;
  const int q31 = lane & 31, hi = lane >> 5;

  const int id = blockIdx.x;                 // 0..511
  const int b = (id & 7) >> 1;               // batch pinned to XCD pair
  const int qt = 127 - 2 * (id >> 3) - (id & 1);   // big tiles dispatched first
  const int q0 = qt * 32;

  const f16* __restrict__ kbase = kh + (size_t)b * T * HS;
  const f16* __restrict__ vbase = vhT + (size_t)b * HS * T;
  const f16* __restrict__ qp = qh + (size_t)(b * T + q0 + q31) * HS + 8 * hi;

  // Q^T as B-operand: lane holds Q[q=lane&31][d = kt*16 + 8*hi + e]
  f16x8 qb[4];
#pragma unroll
  for (int kt = 0; kt < 4; ++kt) qb[kt] = *(const f16x8*)(qp + 16 * kt);

  f32x16 o0, o1;   // O^T d-tiles [0..31], [32..63]
#pragma unroll
  for (int i = 0; i < 16; ++i) { o0[i] = 0.f; o1[i] = 0.f; }
  float m = -1e30f, lsum = 0.f;

  const int nblk = qt + 1;   // causal: KV blocks 0 .. qt
  for (int blk = w; blk < nblk; blk += 8) {
    const int kv0 = blk * 32;
    const f16* kr = kbase + (size_t)(kv0 + q31) * HS + 8 * hi;
    f16x8 ka0 = *(const f16x8*)(kr);
    f16x8 ka1 = *(const f16x8*)(kr + 16);
    f16x8 ka2 = *(const f16x8*)(kr + 32);
    f16x8 ka3 = *(const f16x8*)(kr + 48);

    f32x16 s;
#pragma unroll
    for (int i = 0; i < 16; ++i) s[i] = 0.f;
    s = __builtin_amdgcn_mfma_f32_32x32x16_f16(ka0, qb[0], s, 0, 0, 0);
    s = __builtin_amdgcn_mfma_f32_32x32x16_f16(ka1, qb[1], s, 0, 0, 0);
    s = __builtin_amdgcn_mfma_f32_32x32x16_f16(ka2, qb[2], s, 0, 0, 0);
    s = __builtin_amdgcn_mfma_f32_32x32x16_f16(ka3, qb[3], s, 0, 0, 0);
    // s[reg] = S^T[k = kv0 + (reg&3)+8*(reg>>2)+4*hi][q = q0 + q31]

    // V^T loads issued now, consumed after softmax (hide L2 latency)
    const f16* vr = vbase + (size_t)q31 * T + kv0 + 8 * hi;
    f16x8 v00 = *(const f16x8*)(vr);
    f16x8 v01 = *(const f16x8*)(vr + 16);
    f16x8 v10 = *(const f16x8*)(vr + (size_t)32 * T);
    f16x8 v11 = *(const f16x8*)(vr + (size_t)32 * T + 16);

    if (blk == qt) {   // diagonal block: mask key > q
#pragma unroll
      for (int r = 0; r < 16; ++r) {
        const int kl = (r & 3) + 8 * (r >> 2) + 4 * hi;
        if (kl > q31) s[r] = -1e30f;
      }
    }

    float pm = s[0];
#pragma unroll
    for (int r = 1; r < 16; ++r) pm = fmaxf(pm, s[r]);
    pm = fmaxf(pm, __shfl_xor(pm, 32));
    // defer-max (T13): skip O-rescale while max growth <= 32
    if (!__all(pm <= m + 32.f)) {
      const float mn = fmaxf(m, pm);
      const float r = EXP2((m - mn) * CEXP);
      lsum *= r;
#pragma unroll
      for (int i = 0; i < 16; ++i) { o0[i] *= r; o1[i] *= r; }
      m = mn;
    }

    float p[16];
    float ps = 0.f;
#pragma unroll
    for (int r = 0; r < 16; ++r) { p[r] = EXP2((s[r] - m) * CEXP); ps += p[r]; }
    ps += __shfl_xor(ps, 32);
    lsum += ps;

    u32 c[8], x[8];
#pragma unroll
    for (int i = 0; i < 8; ++i) c[i] = pack2_f16(p[2 * i], p[2 * i + 1]);
#pragma unroll
    for (int i = 0; i < 8; ++i) x[i] = (u32)__shfl_xor((int)c[i], 32);
    union { u32x4 u; f16x8 f; } f1, f2;
    f1.u = (u32x4){ hi ? x[2] : c[0], hi ? x[3] : c[1], hi ? c[2] : x[0], hi ? c[3] : x[1] };
    f2.u = (u32x4){ hi ? x[6] : c[4], hi ? x[7] : c[5], hi ? c[6] : x[4], hi ? c[7] : x[5] };

    o0 = __builtin_amdgcn_mfma_f32_32x32x16_f16(v00, f1.f, o0, 0, 0, 0);
    o0 = __builtin_amdgcn_mfma_f32_32x32x16_f16(v01, f2.f, o0, 0, 0, 0);
    o1 = __builtin_amdgcn_mfma_f32_32x32x16_f16(v10, f1.f, o1, 0, 0, 0);
    o1 = __builtin_amdgcn_mfma_f32_32x32x16_f16(v11, f2.f, o1, 0, 0, 0);
  }

  // ---- cross-wave merge under common max M ----
  if (lane < 32) sMm[w][q31] = m;
  __syncthreads();
  float M = sMm[0][q31];
#pragma unroll
  for (int w2 = 1; w2 < 8; ++w2) M = fmaxf(M, sMm[w2][q31]);
  const float sc = EXP2((m - M) * CEXP);   // idle waves: exp2(-huge)=0
  if (lane < 32) sLs[w][q31] = lsum * sc;
#pragma unroll
  for (int i = 0; i < 16; ++i) { o0[i] *= sc; o1[i] *= sc; }

  if (w >= 4) {
#pragma unroll
    for (int r = 0; r < 16; ++r) {
      const int d = (r & 3) + 8 * (r >> 2) + 4 * hi;
      sO[w - 4][d][q31] = o0[r];
      sO[w - 4][d + 32][q31] = o1[r];
    }
  }
  __syncthreads();
  if (w < 4) {
#pragma unroll
    for (int r = 0; r < 16; ++r) {
      const int d = (r & 3) + 8 * (r >> 2) + 4 * hi;
      sO[w][d][q31] += o0[r];
      sO[w][d + 32][q31] += o1[r];
    }
  }
  __syncthreads();

  // ---- normalize + coalesced float4 store
  const int q = tid >> 4;
  const int d0 = (tid & 15) * 4;
  float L = 0.f;
#pragma unroll
  for (int w2 = 0; w2 < 8; ++w2) L += sLs[w2][q];
  const float invL = 1.f / L;
  float4 rv;
  rv.x = (sO[0][d0 + 0][q] + sO[1][d0 + 0][q] + sO[2][d0 + 0][q] + sO[3][d0 + 0][q]) * invL;
  rv.y = (sO[0][d0 + 1][q] + sO[1][d0 + 1][q] + sO[2][d0 + 1][q] + sO[3][d0 + 1][q]) * invL;
  rv.z = (sO[0][d0 + 2][q] + sO[1][d0 + 2][q] + sO[2][d0 + 2][q] + sO[3][d0 + 2][q]) * invL;
  rv.w = (sO[0][d0 + 3][q] + sO[1][d0 + 3][q] + sO[2][d0 + 3][q] + sO[3][d0 + 3][q]) * invL;
  *(float4*)(out + (size_t)(b * T + q0 + q) * HS + d0) = rv;
}

// ---------------------------------------------------------------------------
extern "C" void kernel_launch(void* const* d_in, const int* in_sizes, int n_in,
                              void* d_out, int out_size, void* d_ws, size_t ws_size,
                              hipStream_t stream) {
  const float* q  = (const float*)d_in[0];
  const float* k  = (const float*)d_in[1];
  const float* v  = (const float*)d_in[2];
  const float* Wq = (const float*)d_in[3];
  const float* Wk = (const float*)d_in[4];
  const float* Wv = (const float*)d_in[5];
  // d_in[6] attn_mask: known lower-triangular causal; handled analytically.
  float* out = (float*)d_out;

  f16* qh  = (f16*)d_ws;                       // [B*T][64]
  f16* kh  = qh  + (size_t)NBATCH * T * HS;    // [B*T][64]
  f16* vhT = kh  + (size_t)NBATCH * T * HS;    // [B][64][T]
  f16* WT  = vhT + (size_t)NBATCH * T * HS;    // [3][64][1024]

  wtrans_kernel<<<dim3(256, 3), 256, 0, stream>>>(Wq, Wk, Wv, WT);
  proj_kernel<<<dim3(256, 3), 256, 0, stream>>>(q, k, v, WT, qh, kh, vhT);
  attn_kernel<<<dim3(T / 32 * NBATCH), 512, 0, stream>>>(qh, kh, vhT, out);
}